// Round 3
// baseline (176.148 us; speedup 1.0000x reference)
//
#include <hip/hip_runtime.h>

// DCNv3 forward, fp32. Layouts (from the reference's view-reshapes):
//   x   : (B=4, H=128, W=128, C=128) flat — idx = ((b*128+h)*128+w)*128+c
//   out : same
//   W_off (128,72), b_off(72), W_mask(128,36), b_mask(36)
// ws: SoA, ws[j*NPIX + pix]; j<72 = offsets (g,p,2), j in [72,108) = softmaxed
// mask (g,p).

#define NPIX 65536  // B*H*W

// ---------------- Kernel A: per-pixel linear layers + mask softmax ---------
// grid 384 = 3 column-groups x 128 pixel-blocks; block 256, 2 pixels/thread
// (each wave-uniform weight value feeds 2x FMAs -> half the scalar-load
// overhead per FLOP).
__global__ __launch_bounds__(256) void dcn_lin(
    const float* __restrict__ x, const float* __restrict__ Woff,
    const float* __restrict__ boff, const float* __restrict__ Wmask,
    const float* __restrict__ bmask, float* __restrict__ ws) {
  const int jg = blockIdx.x >> 7;  // 0,1: offset cols; 2: mask cols
  const int base = (blockIdx.x & 127) << 9;
  const int pixA = base + threadIdx.x;
  const int pixB = pixA + 256;
  const float* W;
  const float* bias;
  int ldw, obase;
  if (jg == 0) {
    W = Woff; bias = boff; ldw = 72; obase = 0;
  } else if (jg == 1) {
    W = Woff + 36; bias = boff + 36; ldw = 72; obase = 36;
  } else {
    W = Wmask; bias = bmask; ldw = 36; obase = 72;
  }

  float accA[36], accB[36];
#pragma unroll
  for (int j = 0; j < 36; ++j) {
    accA[j] = bias[j];
    accB[j] = bias[j];
  }

  const float* xa = x + (size_t)pixA * 128;
  const float* xb = x + (size_t)pixB * 128;
  for (int c0 = 0; c0 < 128; c0 += 8) {
    float xra[8], xrb[8];
    *(float4*)(xra) = *(const float4*)(xa + c0);
    *(float4*)(xra + 4) = *(const float4*)(xa + c0 + 4);
    *(float4*)(xrb) = *(const float4*)(xb + c0);
    *(float4*)(xrb + 4) = *(const float4*)(xb + c0 + 4);
#pragma unroll
    for (int cc = 0; cc < 8; ++cc) {
      const float xcA = xra[cc];
      const float xcB = xrb[cc];
      const float* wr = W + (size_t)(c0 + cc) * ldw;
#pragma unroll
      for (int j = 0; j < 36; ++j) {
        const float wv = wr[j];
        accA[j] = fmaf(xcA, wv, accA[j]);
        accB[j] = fmaf(xcB, wv, accB[j]);
      }
    }
  }

  if (jg == 2) {
#pragma unroll
    for (int g = 0; g < 4; ++g) {
      float mxA = accA[g * 9], mxB = accB[g * 9];
#pragma unroll
      for (int p = 1; p < 9; ++p) {
        mxA = fmaxf(mxA, accA[g * 9 + p]);
        mxB = fmaxf(mxB, accB[g * 9 + p]);
      }
      float sA = 0.f, sB = 0.f;
#pragma unroll
      for (int p = 0; p < 9; ++p) {
        accA[g * 9 + p] = __expf(accA[g * 9 + p] - mxA);
        accB[g * 9 + p] = __expf(accB[g * 9 + p] - mxB);
        sA += accA[g * 9 + p];
        sB += accB[g * 9 + p];
      }
      const float siA = 1.0f / sA, siB = 1.0f / sB;
#pragma unroll
      for (int p = 0; p < 9; ++p) {
        accA[g * 9 + p] *= siA;
        accB[g * 9 + p] *= siB;
      }
    }
  }

#pragma unroll
  for (int j = 0; j < 36; ++j) {
    ws[(size_t)(obase + j) * NPIX + pixA] = accA[j];
    ws[(size_t)(obase + j) * NPIX + pixB] = accB[j];
  }
}

// ---------------- Kernel B: LDS-tiled bilinear gather ----------------
// Block = (8x8 pixel tile) x (1 group, 32 ch). Stage 19x19 positions x 32 ch
// (margin 4) into LDS, zero-filled outside the image (== reference's
// zero-weight pad semantics). Position stride 36 floats: 16B-aligned b128
// reads, +4-bank shift per position. Off-tile samples (|off| beyond ~3) take
// a clamped-global fallback identical to the reference.
#define TH 19
#define PSTRIDE 36

__global__ __launch_bounds__(256) void dcn_samp(
    const float* __restrict__ x, const float* __restrict__ ws,
    float* __restrict__ out) {
  __shared__ float lds[361 * PSTRIDE];  // 51,984 B

  const int g = blockIdx.x & 3;
  const int tile = blockIdx.x >> 2;
  const int bb = tile >> 8;
  const int tyt = (tile >> 4) & 15;
  const int txt = tile & 15;
  const int h0 = tyt << 3, w0 = txt << 3;
  const int ty0 = h0 - 4, tx0 = w0 - 4;
  const int g32 = g << 5;

  // ---- stage tile: thread = (pos = t>>3 per iter, ch4 = t&7) ----
  {
    const int ch4 = (threadIdx.x & 7) << 2;
    for (int k = 0; k < 12; ++k) {
      const int pos = (k << 5) + (threadIdx.x >> 3);
      if (pos < 361) {
        const int ry = pos / TH, rx = pos - ry * TH;
        const int y = ty0 + ry, xc = tx0 + rx;
        float4 v = make_float4(0.f, 0.f, 0.f, 0.f);
        if ((unsigned)y < 128u && (unsigned)xc < 128u)
          v = *(const float4*)(x +
                               ((((size_t)((bb << 7) | y) << 7) | xc) << 7) +
                               g32 + ch4);
        *(float4*)(lds + pos * PSTRIDE + ch4) = v;
      }
    }
  }
  __syncthreads();

  // ---- gather: thread = (px_l = t>>2, sub = t&3 -> 8 channels) ----
  const int px_l = threadIdx.x >> 2;
  const int sub = threadIdx.x & 3;
  const int yy = px_l >> 3, xx = px_l & 7;
  const int h = h0 + yy, w = w0 + xx;
  const int q = (bb << 14) | (h << 7) | w;
  const float* wsq = ws + q;
  const float* xg = x + ((size_t)bb << 21) + g32 + (sub << 3);

  float offx9[9], offy9[9], mk9[9];
#pragma unroll
  for (int p = 0; p < 9; ++p) {
    offx9[p] = wsq[(size_t)(g * 18 + p * 2) * NPIX];
    offy9[p] = wsq[(size_t)(g * 18 + p * 2 + 1) * NPIX];
    mk9[p] = wsq[(size_t)(72 + g * 9 + p) * NPIX];
  }

  float a0 = 0.f, a1 = 0.f, a2 = 0.f, a3 = 0.f;
  float a4 = 0.f, a5 = 0.f, a6 = 0.f, a7 = 0.f;
#pragma unroll
  for (int p = 0; p < 9; ++p) {
    const float mk = mk9[p];
    const float px = (float)(w + p / 3) + offx9[p];
    const float py = (float)(h + p % 3) + offy9[p];
    const float fx = floorf(px), fy = floorf(py);
    const float tx = px - fx, ty = py - fy;
    const int x0 = (int)fx - 1, y0 = (int)fy - 1;
    const int xc = x0 - tx0, yc = y0 - ty0;
    float w00, w10, w01, w11;
    float4 vA00, vB00, vA10, vB10, vA01, vB01, vA11, vB11;
    if ((unsigned)xc < 18u && (unsigned)yc < 18u) {
      const int fbase = (yc * TH + xc) * PSTRIDE + (sub << 3);
      vA00 = *(const float4*)(lds + fbase);
      vB00 = *(const float4*)(lds + fbase + 4);
      vA10 = *(const float4*)(lds + fbase + PSTRIDE);
      vB10 = *(const float4*)(lds + fbase + PSTRIDE + 4);
      vA01 = *(const float4*)(lds + fbase + TH * PSTRIDE);
      vB01 = *(const float4*)(lds + fbase + TH * PSTRIDE + 4);
      vA11 = *(const float4*)(lds + fbase + (TH + 1) * PSTRIDE);
      vB11 = *(const float4*)(lds + fbase + (TH + 1) * PSTRIDE + 4);
      const float my0 = mk * (1.f - ty), my1 = mk * ty;
      w00 = (1.f - tx) * my0;
      w10 = tx * my0;
      w01 = (1.f - tx) * my1;
      w11 = tx * my1;
    } else {
      // clamped-global fallback, validity folded into weights
      const int x1 = x0 + 1, y1 = y0 + 1;
      const float ax0 = ((unsigned)x0 < 128u) ? (1.f - tx) : 0.f;
      const float ax1 = ((unsigned)x1 < 128u) ? tx : 0.f;
      const float ay0 = ((unsigned)y0 < 128u) ? (mk * (1.f - ty)) : 0.f;
      const float ay1 = ((unsigned)y1 < 128u) ? (mk * ty) : 0.f;
      w00 = ax0 * ay0;
      w10 = ax1 * ay0;
      w01 = ax0 * ay1;
      w11 = ax1 * ay1;
      const int cx0 = min(max(x0, 0), 127), cy0 = min(max(y0, 0), 127);
      const int cx1 = min(max(x1, 0), 127), cy1 = min(max(y1, 0), 127);
      const int o00 = (cy0 << 14) | (cx0 << 7), o10 = (cy0 << 14) | (cx1 << 7);
      const int o01 = (cy1 << 14) | (cx0 << 7), o11 = (cy1 << 14) | (cx1 << 7);
      vA00 = *(const float4*)(xg + o00);
      vB00 = *(const float4*)(xg + o00 + 4);
      vA10 = *(const float4*)(xg + o10);
      vB10 = *(const float4*)(xg + o10 + 4);
      vA01 = *(const float4*)(xg + o01);
      vB01 = *(const float4*)(xg + o01 + 4);
      vA11 = *(const float4*)(xg + o11);
      vB11 = *(const float4*)(xg + o11 + 4);
    }
    a0 = fmaf(w00, vA00.x, fmaf(w10, vA10.x, fmaf(w01, vA01.x, fmaf(w11, vA11.x, a0))));
    a1 = fmaf(w00, vA00.y, fmaf(w10, vA10.y, fmaf(w01, vA01.y, fmaf(w11, vA11.y, a1))));
    a2 = fmaf(w00, vA00.z, fmaf(w10, vA10.z, fmaf(w01, vA01.z, fmaf(w11, vA11.z, a2))));
    a3 = fmaf(w00, vA00.w, fmaf(w10, vA10.w, fmaf(w01, vA01.w, fmaf(w11, vA11.w, a3))));
    a4 = fmaf(w00, vB00.x, fmaf(w10, vB10.x, fmaf(w01, vB01.x, fmaf(w11, vB11.x, a4))));
    a5 = fmaf(w00, vB00.y, fmaf(w10, vB10.y, fmaf(w01, vB01.y, fmaf(w11, vB11.y, a5))));
    a6 = fmaf(w00, vB00.z, fmaf(w10, vB10.z, fmaf(w01, vB01.z, fmaf(w11, vB11.z, a6))));
    a7 = fmaf(w00, vB00.w, fmaf(w10, vB10.w, fmaf(w01, vB01.w, fmaf(w11, vB11.w, a7))));
  }
  float4 oa, ob;
  oa.x = a0; oa.y = a1; oa.z = a2; oa.w = a3;
  ob.x = a4; ob.y = a5; ob.z = a6; ob.w = a7;
  float* op = out + (size_t)q * 128 + g32 + (sub << 3);
  *(float4*)op = oa;
  *(float4*)(op + 4) = ob;
}

// ---------------- Fallback: fully fused, one pixel per 128-thread block ----
__global__ __launch_bounds__(128) void dcn_fused(
    const float* __restrict__ x, const float* __restrict__ Woff,
    const float* __restrict__ boff, const float* __restrict__ Wmask,
    const float* __restrict__ bmask, float* __restrict__ out) {
  __shared__ float xs[128];
  __shared__ float res[108];
  __shared__ float msk[36];
  const int q = blockIdx.x;
  const int t = threadIdx.x;
  const int b = q >> 14, h = (q >> 7) & 127, w = q & 127;
  xs[t] = x[(size_t)q * 128 + t];
  __syncthreads();
  if (t < 108) {
    float a;
    const float* W;
    int ld;
    if (t < 72) {
      a = boff[t]; W = Woff + t; ld = 72;
    } else {
      a = bmask[t - 72]; W = Wmask + (t - 72); ld = 36;
    }
    for (int cc = 0; cc < 128; ++cc) a = fmaf(xs[cc], W[(size_t)cc * ld], a);
    res[t] = a;
  }
  __syncthreads();
  if (t < 4) {
    float mx = -1e30f;
    for (int p = 0; p < 9; ++p) mx = fmaxf(mx, res[72 + t * 9 + p]);
    float s = 0.f;
    float e[9];
    for (int p = 0; p < 9; ++p) {
      e[p] = __expf(res[72 + t * 9 + p] - mx);
      s += e[p];
    }
    for (int p = 0; p < 9; ++p) msk[t * 9 + p] = e[p] / s;
  }
  __syncthreads();
  const int g = t >> 5;
  const float* xb = x + ((size_t)b << 21) + t;
  float acc = 0.f;
#pragma unroll
  for (int p = 0; p < 9; ++p) {
    const float offx = res[g * 18 + p * 2];
    const float offy = res[g * 18 + p * 2 + 1];
    const float px = (float)(w + p / 3) + offx;
    const float py = (float)(h + p % 3) + offy;
    const float fx = floorf(px), fy = floorf(py);
    const float tx = px - fx, ty = py - fy;
    const int x0 = (int)fx - 1, y0 = (int)fy - 1;
    float sv = 0.f;
#define CORNER1(XI, YI, WT)                                       \
  if ((unsigned)(XI) < 128u && (unsigned)(YI) < 128u)             \
    sv = fmaf((WT), xb[((size_t)(YI) << 14) + ((size_t)(XI) << 7)], sv);
    CORNER1(x0, y0, (1.f - tx) * (1.f - ty))
    CORNER1(x0 + 1, y0, tx * (1.f - ty))
    CORNER1(x0, y0 + 1, (1.f - tx) * ty)
    CORNER1(x0 + 1, y0 + 1, tx * ty)
#undef CORNER1
    acc = fmaf(msk[g * 9 + p], sv, acc);
  }
  out[(size_t)q * 128 + t] = acc;
}

extern "C" void kernel_launch(void* const* d_in, const int* in_sizes, int n_in,
                              void* d_out, int out_size, void* d_ws,
                              size_t ws_size, hipStream_t stream) {
  const float* x = (const float*)d_in[0];
  const float* Woff = (const float*)d_in[1];
  const float* boff = (const float*)d_in[2];
  const float* Wmask = (const float*)d_in[3];
  const float* bmask = (const float*)d_in[4];
  float* out = (float*)d_out;
  const size_t need = (size_t)NPIX * 108 * sizeof(float);
  if (ws_size >= need) {
    float* ws = (float*)d_ws;
    dcn_lin<<<384, 256, 0, stream>>>(x, Woff, boff, Wmask, bmask, ws);
    dcn_samp<<<4096, 256, 0, stream>>>(x, ws, out);
  } else {
    dcn_fused<<<NPIX, 128, 0, stream>>>(x, Woff, boff, Wmask, bmask, out);
  }
}

// Round 4
// 98.395 us; speedup vs baseline: 1.7902x; 1.7902x over previous
//
#include <hip/hip_runtime.h>

// DCNv3 forward, fp32. Layouts (from the reference's view-reshapes):
//   x   : (B=4, H=128, W=128, C=128) flat — idx = ((b*128+h)*128+w)*128+c
//   out : same
//   W_off (128,72), b_off(72), W_mask(128,36), b_mask(36)
// ws: [0, 108*NPIX) floats : SoA ws[j*NPIX + pix]; j<72 = offsets (g,p,2),
//     j in [72,108) = softmaxed mask (g,p).
//     [108*NPIX floats ...) : x16 — bf16 copy of x, GROUP-PLANAR:
//     x16[((g*4+b)*16384 + y*128 + x)*32 + ch]  (ch in [0,32) within group)
// Group-planar bf16 halves gather bytes and makes the 4 corners of a sample
// span 2 cache lines densely (x0,x0+1 are adjacent 64B chunks).

#define NPIX 65536  // B*H*W

typedef unsigned int uint;
typedef unsigned short ushort;

__device__ __forceinline__ ushort f2bf(float f) {
  uint u = __float_as_uint(f);
  u += 0x7FFFu + ((u >> 16) & 1u);  // RNE
  return (ushort)(u >> 16);
}
__device__ __forceinline__ uint pkbf(float lo, float hi) {
  return (uint)f2bf(lo) | ((uint)f2bf(hi) << 16);
}
__device__ __forceinline__ float bflo(uint d) { return __uint_as_float(d << 16); }
__device__ __forceinline__ float bfhi(uint d) { return __uint_as_float(d & 0xFFFF0000u); }

// ---------------- Kernel A: per-pixel linear layers + softmax + bf16 pack --
__global__ __launch_bounds__(256) void dcn_lin(
    const float* __restrict__ x, const float* __restrict__ Woff,
    const float* __restrict__ boff, const float* __restrict__ Wmask,
    const float* __restrict__ bmask, float* __restrict__ ws,
    ushort* __restrict__ x16) {
  const int jg = blockIdx.x >> 8;  // 0,1: offset cols; 2: mask cols
  const int pix = ((blockIdx.x & 255) << 8) | threadIdx.x;
  const float* W;
  const float* bias;
  int ldw, obase;
  if (jg == 0) {
    W = Woff; bias = boff; ldw = 72; obase = 0;
  } else if (jg == 1) {
    W = Woff + 36; bias = boff + 36; ldw = 72; obase = 36;
  } else {
    W = Wmask; bias = bmask; ldw = 36; obase = 72;
  }

  float acc[36];
#pragma unroll
  for (int j = 0; j < 36; ++j) acc[j] = bias[j];

  const float* xp = x + (size_t)pix * 128;
  for (int c0 = 0; c0 < 128; c0 += 8) {
    float xr[8];
    *(float4*)(xr) = *(const float4*)(xp + c0);
    *(float4*)(xr + 4) = *(const float4*)(xp + c0 + 4);
#pragma unroll
    for (int cc = 0; cc < 8; ++cc) {
      const float xc = xr[cc];
      const float* wr = W + (size_t)(c0 + cc) * ldw;
#pragma unroll
      for (int j = 0; j < 36; ++j) acc[j] = fmaf(xc, wr[j], acc[j]);
    }
  }

  if (jg == 2) {
#pragma unroll
    for (int g = 0; g < 4; ++g) {
      float mx = acc[g * 9];
#pragma unroll
      for (int p = 1; p < 9; ++p) mx = fmaxf(mx, acc[g * 9 + p]);
      float s = 0.f;
#pragma unroll
      for (int p = 0; p < 9; ++p) {
        acc[g * 9 + p] = __expf(acc[g * 9 + p] - mx);
        s += acc[g * 9 + p];
      }
      const float sinv = 1.0f / s;
#pragma unroll
      for (int p = 0; p < 9; ++p) acc[g * 9 + p] *= sinv;
    }
  }

#pragma unroll
  for (int j = 0; j < 36; ++j) ws[(size_t)(obase + j) * NPIX + pix] = acc[j];

  if (jg == 0 && x16 != nullptr) {
    const int bb = pix >> 14;
    const int yx = pix & 16383;
#pragma unroll
    for (int g = 0; g < 4; ++g) {
      ushort* dst = x16 + ((((size_t)((g << 2) | bb) << 14) | yx) << 5);
#pragma unroll
      for (int ck = 0; ck < 2; ++ck) {
        const float4 a = *(const float4*)(xp + g * 32 + ck * 16);
        const float4 b4 = *(const float4*)(xp + g * 32 + ck * 16 + 4);
        const float4 c4 = *(const float4*)(xp + g * 32 + ck * 16 + 8);
        const float4 d4 = *(const float4*)(xp + g * 32 + ck * 16 + 12);
        uint4 s0, s1;
        s0.x = pkbf(a.x, a.y);   s0.y = pkbf(a.z, a.w);
        s0.z = pkbf(b4.x, b4.y); s0.w = pkbf(b4.z, b4.w);
        s1.x = pkbf(c4.x, c4.y); s1.y = pkbf(c4.z, c4.w);
        s1.z = pkbf(d4.x, d4.y); s1.w = pkbf(d4.z, d4.w);
        *(uint4*)(dst + ck * 16) = s0;
        *(uint4*)(dst + ck * 16 + 8) = s1;
      }
    }
  }
}

// ---------------- Kernel B: bilinear gather from bf16 planar ---------------
// block 256 = 256 consecutive pixels (2 rows), one group per block
// (g = blockIdx&3). Lane covers its pixel's full 32-channel group slice.
__global__ __launch_bounds__(256) void dcn_samp(
    const ushort* __restrict__ x16, const float* __restrict__ ws,
    float* __restrict__ out) {
  const int g = blockIdx.x & 3;
  const int q = ((blockIdx.x >> 2) << 8) | threadIdx.x;
  const int b = q >> 14;
  const int h = (q >> 7) & 127;
  const int w = q & 127;
  const float* wsq = ws + q;
  const ushort* xg = x16 + (((size_t)((g << 2) | b) << 14) << 5);

  float acc[32];
#pragma unroll
  for (int i = 0; i < 32; ++i) acc[i] = 0.f;

  for (int p = 0; p < 9; ++p) {
    const float offx = wsq[(size_t)(g * 18 + 2 * p) * NPIX];
    const float offy = wsq[(size_t)(g * 18 + 2 * p + 1) * NPIX];
    const float mk = wsq[(size_t)(72 + g * 9 + p) * NPIX];
    const float px = (float)(w + p / 3) + offx;
    const float py = (float)(h + p % 3) + offy;
    const float fx = floorf(px), fy = floorf(py);
    const float tx = px - fx, ty = py - fy;
    const int x0 = (int)fx - 1, y0 = (int)fy - 1;
    const int x1 = x0 + 1, y1 = y0 + 1;
    const float ax0 = ((unsigned)x0 < 128u) ? (1.f - tx) : 0.f;
    const float ax1 = ((unsigned)x1 < 128u) ? tx : 0.f;
    const float ay0 = ((unsigned)y0 < 128u) ? (mk * (1.f - ty)) : 0.f;
    const float ay1 = ((unsigned)y1 < 128u) ? (mk * ty) : 0.f;
    const float w00 = ax0 * ay0, w10 = ax1 * ay0;
    const float w01 = ax0 * ay1, w11 = ax1 * ay1;
    const int cx0 = min(max(x0, 0), 127), cy0 = min(max(y0, 0), 127);
    const int cx1 = min(max(x1, 0), 127), cy1 = min(max(y1, 0), 127);
    const int o00 = ((cy0 << 7) | cx0) << 5;
    const int o10 = ((cy0 << 7) | cx1) << 5;
    const int o01 = ((cy1 << 7) | cx0) << 5;
    const int o11 = ((cy1 << 7) | cx1) << 5;
#pragma unroll
    for (int ck = 0; ck < 4; ++ck) {  // 8 channels per chunk
      const int co = ck << 3;
      const uint4 d00 = *(const uint4*)(xg + o00 + co);
      const uint4 d10 = *(const uint4*)(xg + o10 + co);
      const uint4 d01 = *(const uint4*)(xg + o01 + co);
      const uint4 d11 = *(const uint4*)(xg + o11 + co);
#define ACC2(K, E)                                                          \
  acc[co + 2 * K] = fmaf(w00, bflo(d00.E),                                  \
      fmaf(w10, bflo(d10.E), fmaf(w01, bflo(d01.E),                         \
      fmaf(w11, bflo(d11.E), acc[co + 2 * K]))));                           \
  acc[co + 2 * K + 1] = fmaf(w00, bfhi(d00.E),                              \
      fmaf(w10, bfhi(d10.E), fmaf(w01, bfhi(d01.E),                         \
      fmaf(w11, bfhi(d11.E), acc[co + 2 * K + 1]))));
      ACC2(0, x) ACC2(1, y) ACC2(2, z) ACC2(3, w)
#undef ACC2
    }
  }

  float* op = out + (size_t)q * 128 + (g << 5);
#pragma unroll
  for (int i = 0; i < 8; ++i) {
    float4 v;
    v.x = acc[i * 4]; v.y = acc[i * 4 + 1];
    v.z = acc[i * 4 + 2]; v.w = acc[i * 4 + 3];
    *(float4*)(op + i * 4) = v;
  }
}

// ---------------- Tier-2 fallback: R2's proven fp32 gather ----------------
__global__ __launch_bounds__(256) void dcn_samp_f32(
    const float* __restrict__ x, const float* __restrict__ ws,
    float* __restrict__ out) {
  const int q = (blockIdx.x << 4) | (threadIdx.x >> 4);
  const int sub = threadIdx.x & 15;
  const int c = sub << 3;
  const int g = sub >> 2;
  const int b = q >> 14;
  const int h = (q >> 7) & 127;
  const int w = q & 127;
  const float* xb = x + ((size_t)b << 21) + c;
  const float* wsq = ws + q;
  float a0 = 0.f, a1 = 0.f, a2 = 0.f, a3 = 0.f;
  float a4 = 0.f, a5 = 0.f, a6 = 0.f, a7 = 0.f;
#pragma unroll
  for (int p = 0; p < 9; ++p) {
    const float offx = wsq[(size_t)(g * 18 + p * 2) * NPIX];
    const float offy = wsq[(size_t)(g * 18 + p * 2 + 1) * NPIX];
    const float mk = wsq[(size_t)(72 + g * 9 + p) * NPIX];
    const float px = (float)(w + p / 3) + offx;
    const float py = (float)(h + p % 3) + offy;
    const float fx = floorf(px), fy = floorf(py);
    const float tx = px - fx, ty = py - fy;
    const int x0 = (int)fx - 1, y0 = (int)fy - 1;
    const int x1 = x0 + 1, y1 = y0 + 1;
    const float ax0 = ((unsigned)x0 < 128u) ? (1.f - tx) : 0.f;
    const float ax1 = ((unsigned)x1 < 128u) ? tx : 0.f;
    const float ay0 = ((unsigned)y0 < 128u) ? (mk * (1.f - ty)) : 0.f;
    const float ay1 = ((unsigned)y1 < 128u) ? (mk * ty) : 0.f;
    const float w00 = ax0 * ay0, w10 = ax1 * ay0;
    const float w01 = ax0 * ay1, w11 = ax1 * ay1;
    const int cx0 = min(max(x0, 0), 127), cy0 = min(max(y0, 0), 127);
    const int cx1 = min(max(x1, 0), 127), cy1 = min(max(y1, 0), 127);
    const int o00 = (cy0 << 14) | (cx0 << 7), o10 = (cy0 << 14) | (cx1 << 7);
    const int o01 = (cy1 << 14) | (cx0 << 7), o11 = (cy1 << 14) | (cx1 << 7);
    const float4 v00a = *(const float4*)(xb + o00);
    const float4 v00b = *(const float4*)(xb + o00 + 4);
    const float4 v10a = *(const float4*)(xb + o10);
    const float4 v10b = *(const float4*)(xb + o10 + 4);
    const float4 v01a = *(const float4*)(xb + o01);
    const float4 v01b = *(const float4*)(xb + o01 + 4);
    const float4 v11a = *(const float4*)(xb + o11);
    const float4 v11b = *(const float4*)(xb + o11 + 4);
    a0 = fmaf(w00, v00a.x, fmaf(w10, v10a.x, fmaf(w01, v01a.x, fmaf(w11, v11a.x, a0))));
    a1 = fmaf(w00, v00a.y, fmaf(w10, v10a.y, fmaf(w01, v01a.y, fmaf(w11, v11a.y, a1))));
    a2 = fmaf(w00, v00a.z, fmaf(w10, v10a.z, fmaf(w01, v01a.z, fmaf(w11, v11a.z, a2))));
    a3 = fmaf(w00, v00a.w, fmaf(w10, v10a.w, fmaf(w01, v01a.w, fmaf(w11, v11a.w, a3))));
    a4 = fmaf(w00, v00b.x, fmaf(w10, v10b.x, fmaf(w01, v01b.x, fmaf(w11, v11b.x, a4))));
    a5 = fmaf(w00, v00b.y, fmaf(w10, v10b.y, fmaf(w01, v01b.y, fmaf(w11, v11b.y, a5))));
    a6 = fmaf(w00, v00b.z, fmaf(w10, v10b.z, fmaf(w01, v01b.z, fmaf(w11, v11b.z, a6))));
    a7 = fmaf(w00, v00b.w, fmaf(w10, v10b.w, fmaf(w01, v01b.w, fmaf(w11, v11b.w, a7))));
  }
  float4 oa, ob;
  oa.x = a0; oa.y = a1; oa.z = a2; oa.w = a3;
  ob.x = a4; ob.y = a5; ob.z = a6; ob.w = a7;
  float* op = out + (size_t)q * 128 + c;
  *(float4*)op = oa;
  *(float4*)(op + 4) = ob;
}

// ---------------- Tier-3 fallback: fully fused ----------------
__global__ __launch_bounds__(128) void dcn_fused(
    const float* __restrict__ x, const float* __restrict__ Woff,
    const float* __restrict__ boff, const float* __restrict__ Wmask,
    const float* __restrict__ bmask, float* __restrict__ out) {
  __shared__ float xs[128];
  __shared__ float res[108];
  __shared__ float msk[36];
  const int q = blockIdx.x;
  const int t = threadIdx.x;
  const int b = q >> 14, h = (q >> 7) & 127, w = q & 127;
  xs[t] = x[(size_t)q * 128 + t];
  __syncthreads();
  if (t < 108) {
    float a;
    const float* W;
    int ld;
    if (t < 72) {
      a = boff[t]; W = Woff + t; ld = 72;
    } else {
      a = bmask[t - 72]; W = Wmask + (t - 72); ld = 36;
    }
    for (int cc = 0; cc < 128; ++cc) a = fmaf(xs[cc], W[(size_t)cc * ld], a);
    res[t] = a;
  }
  __syncthreads();
  if (t < 4) {
    float mx = -1e30f;
    for (int p = 0; p < 9; ++p) mx = fmaxf(mx, res[72 + t * 9 + p]);
    float s = 0.f;
    float e[9];
    for (int p = 0; p < 9; ++p) {
      e[p] = __expf(res[72 + t * 9 + p] - mx);
      s += e[p];
    }
    for (int p = 0; p < 9; ++p) msk[t * 9 + p] = e[p] / s;
  }
  __syncthreads();
  const int g = t >> 5;
  const float* xb = x + ((size_t)b << 21) + t;
  float acc = 0.f;
#pragma unroll
  for (int p = 0; p < 9; ++p) {
    const float offx = res[g * 18 + p * 2];
    const float offy = res[g * 18 + p * 2 + 1];
    const float px = (float)(w + p / 3) + offx;
    const float py = (float)(h + p % 3) + offy;
    const float fx = floorf(px), fy = floorf(py);
    const float tx = px - fx, ty = py - fy;
    const int x0 = (int)fx - 1, y0 = (int)fy - 1;
    float sv = 0.f;
#define CORNER1(XI, YI, WT)                                       \
  if ((unsigned)(XI) < 128u && (unsigned)(YI) < 128u)             \
    sv = fmaf((WT), xb[((size_t)(YI) << 14) + ((size_t)(XI) << 7)], sv);
    CORNER1(x0, y0, (1.f - tx) * (1.f - ty))
    CORNER1(x0 + 1, y0, tx * (1.f - ty))
    CORNER1(x0, y0 + 1, (1.f - tx) * ty)
    CORNER1(x0 + 1, y0 + 1, tx * ty)
#undef CORNER1
    acc = fmaf(msk[g * 9 + p], sv, acc);
  }
  out[(size_t)q * 128 + t] = acc;
}

extern "C" void kernel_launch(void* const* d_in, const int* in_sizes, int n_in,
                              void* d_out, int out_size, void* d_ws,
                              size_t ws_size, hipStream_t stream) {
  const float* x = (const float*)d_in[0];
  const float* Woff = (const float*)d_in[1];
  const float* boff = (const float*)d_in[2];
  const float* Wmask = (const float*)d_in[3];
  const float* bmask = (const float*)d_in[4];
  float* out = (float*)d_out;
  const size_t need_ws = (size_t)NPIX * 108 * sizeof(float);
  const size_t need_full = need_ws + (size_t)NPIX * 128 * sizeof(ushort);
  if (ws_size >= need_full) {
    float* ws = (float*)d_ws;
    ushort* x16 = (ushort*)((char*)d_ws + need_ws);
    dcn_lin<<<768, 256, 0, stream>>>(x, Woff, boff, Wmask, bmask, ws, x16);
    dcn_samp<<<1024, 256, 0, stream>>>(x16, ws, out);
  } else if (ws_size >= need_ws) {
    float* ws = (float*)d_ws;
    dcn_lin<<<768, 256, 0, stream>>>(x, Woff, boff, Wmask, bmask, ws,
                                     (ushort*)nullptr);
    dcn_samp_f32<<<4096, 256, 0, stream>>>(x, ws, out);
  } else {
    dcn_fused<<<NPIX, 128, 0, stream>>>(x, Woff, boff, Wmask, bmask, out);
  }
}

// Round 5
// 90.992 us; speedup vs baseline: 1.9359x; 1.0814x over previous
//
#include <hip/hip_runtime.h>

// DCNv3 forward, fp32. Layouts (from the reference's view-reshapes):
//   x   : (B=4, H=128, W=128, C=128) flat — idx = ((b*128+h)*128+w)*128+c
//   out : same
//   W_off (128,72), b_off(72), W_mask(128,36), b_mask(36)
// ws: [0, 108*NPIX) floats : SoA ws[j*NPIX + pix]; j<72 = offsets (g,p,2),
//     j in [72,108) = softmaxed mask (g,p).
//     [108*NPIX floats ...) : x16 — bf16 copy of x, GROUP-PLANAR:
//     x16[((g*4+b)*16384 + y*128 + x)*32 + ch]  (ch in [0,32) within group)

#define NPIX 65536  // B*H*W

typedef unsigned int uint;
typedef unsigned short ushort;

__device__ __forceinline__ ushort f2bf(float f) {
  uint u = __float_as_uint(f);
  u += 0x7FFFu + ((u >> 16) & 1u);  // RNE
  return (ushort)(u >> 16);
}
__device__ __forceinline__ uint pkbf(float lo, float hi) {
  return (uint)f2bf(lo) | ((uint)f2bf(hi) << 16);
}
__device__ __forceinline__ float bflo(uint d) { return __uint_as_float(d << 16); }
__device__ __forceinline__ float bfhi(uint d) { return __uint_as_float(d & 0xFFFF0000u); }

// ---------------- Kernel A: linear layers (6-way col split) + softmax,
// plus 256 dedicated bf16-pack blocks.
// grid 1792 = 6 col-groups x 256 pixel-blocks + 256 pack blocks; block 256.
__global__ __launch_bounds__(256) void dcn_lin(
    const float* __restrict__ x, const float* __restrict__ Woff,
    const float* __restrict__ boff, const float* __restrict__ Wmask,
    const float* __restrict__ bmask, float* __restrict__ ws,
    ushort* __restrict__ x16) {
  const int bid = blockIdx.x;

  if (bid >= 1536) {  // ---- bf16 group-planar pack ----
    if (x16 == nullptr) return;
    const int pix = ((bid - 1536) << 8) | threadIdx.x;
    const float* xp = x + (size_t)pix * 128;
    const int bb = pix >> 14;
    const int yx = pix & 16383;
#pragma unroll
    for (int g = 0; g < 4; ++g) {
      ushort* dst = x16 + ((((size_t)((g << 2) | bb) << 14) | yx) << 5);
#pragma unroll
      for (int ck = 0; ck < 2; ++ck) {
        const float4 a = *(const float4*)(xp + g * 32 + ck * 16);
        const float4 b4 = *(const float4*)(xp + g * 32 + ck * 16 + 4);
        const float4 c4 = *(const float4*)(xp + g * 32 + ck * 16 + 8);
        const float4 d4 = *(const float4*)(xp + g * 32 + ck * 16 + 12);
        uint4 s0, s1;
        s0.x = pkbf(a.x, a.y);   s0.y = pkbf(a.z, a.w);
        s0.z = pkbf(b4.x, b4.y); s0.w = pkbf(b4.z, b4.w);
        s1.x = pkbf(c4.x, c4.y); s1.y = pkbf(c4.z, c4.w);
        s1.z = pkbf(d4.x, d4.y); s1.w = pkbf(d4.z, d4.w);
        *(uint4*)(dst + ck * 16) = s0;
        *(uint4*)(dst + ck * 16 + 8) = s1;
      }
    }
    return;
  }

  // ---- linear compute: 18 output columns per block-group ----
  const int jg = bid >> 8;  // 0..3: offset col-halves (one g each); 4,5: mask
  const int pix = ((bid & 255) << 8) | threadIdx.x;
  const float* W;
  const float* bias;
  int ldw, obase;
  if (jg < 4) {
    W = Woff + jg * 18; bias = boff + jg * 18; ldw = 72; obase = jg * 18;
  } else if (jg == 4) {
    W = Wmask; bias = bmask; ldw = 36; obase = 72;
  } else {
    W = Wmask + 18; bias = bmask + 18; ldw = 36; obase = 90;
  }

  float acc[18];
#pragma unroll
  for (int j = 0; j < 18; ++j) acc[j] = bias[j];

  const float* xp = x + (size_t)pix * 128;
  for (int c0 = 0; c0 < 128; c0 += 8) {
    float xr[8];
    *(float4*)(xr) = *(const float4*)(xp + c0);
    *(float4*)(xr + 4) = *(const float4*)(xp + c0 + 4);
#pragma unroll
    for (int cc = 0; cc < 8; ++cc) {
      const float xc = xr[cc];
      const float* wr = W + (size_t)(c0 + cc) * ldw;
#pragma unroll
      for (int j = 0; j < 18; ++j) acc[j] = fmaf(xc, wr[j], acc[j]);
    }
  }

  if (jg >= 4) {  // softmax over the two 9-col groups in this half
#pragma unroll
    for (int gg = 0; gg < 2; ++gg) {
      float mx = acc[gg * 9];
#pragma unroll
      for (int p = 1; p < 9; ++p) mx = fmaxf(mx, acc[gg * 9 + p]);
      float s = 0.f;
#pragma unroll
      for (int p = 0; p < 9; ++p) {
        acc[gg * 9 + p] = __expf(acc[gg * 9 + p] - mx);
        s += acc[gg * 9 + p];
      }
      const float sinv = 1.0f / s;
#pragma unroll
      for (int p = 0; p < 9; ++p) acc[gg * 9 + p] *= sinv;
    }
  }

#pragma unroll
  for (int j = 0; j < 18; ++j) ws[(size_t)(obase + j) * NPIX + pix] = acc[j];
}

// ---------------- Kernel B: bilinear gather from bf16 planar ---------------
// block 256 = 64 (pixel,group) pairs x 4 chunk-lanes; g = blockIdx&3.
// A wave = 16 consecutive pixels x 4 lanes; the 4 lanes cover the group's
// 64B slice contiguously, so each corner is ONE dwordx4 inst whose lanes
// touch ~16 cache lines (dense) instead of 32 (sparse).
__global__ __launch_bounds__(256) void dcn_samp(
    const ushort* __restrict__ x16, const float* __restrict__ ws,
    float* __restrict__ out) {
  const int g = blockIdx.x & 3;
  const int pg = threadIdx.x >> 2;   // 0..63: pixel within block
  const int sub = threadIdx.x & 3;   // 16B chunk within the group slice
  const int q = ((blockIdx.x >> 2) << 6) | pg;
  const int b = q >> 14;
  const int h = (q >> 7) & 127;
  const int w = q & 127;
  const float* wsq = ws + q;
  const ushort* xg = x16 + (((size_t)((g << 2) | b) << 14) << 5) + (sub << 3);

  float a0 = 0.f, a1 = 0.f, a2 = 0.f, a3 = 0.f;
  float a4 = 0.f, a5 = 0.f, a6 = 0.f, a7 = 0.f;

#pragma unroll
  for (int p = 0; p < 9; ++p) {
    const float offx = wsq[(size_t)(g * 18 + 2 * p) * NPIX];
    const float offy = wsq[(size_t)(g * 18 + 2 * p + 1) * NPIX];
    const float mk = wsq[(size_t)(72 + g * 9 + p) * NPIX];
    const float px = (float)(w + p / 3) + offx;
    const float py = (float)(h + p % 3) + offy;
    const float fx = floorf(px), fy = floorf(py);
    const float tx = px - fx, ty = py - fy;
    const int x0 = (int)fx - 1, y0 = (int)fy - 1;
    const int x1 = x0 + 1, y1 = y0 + 1;
    const float ax0 = ((unsigned)x0 < 128u) ? (1.f - tx) : 0.f;
    const float ax1 = ((unsigned)x1 < 128u) ? tx : 0.f;
    const float ay0 = ((unsigned)y0 < 128u) ? (mk * (1.f - ty)) : 0.f;
    const float ay1 = ((unsigned)y1 < 128u) ? (mk * ty) : 0.f;
    const float w00 = ax0 * ay0, w10 = ax1 * ay0;
    const float w01 = ax0 * ay1, w11 = ax1 * ay1;
    const int cx0 = min(max(x0, 0), 127), cy0 = min(max(y0, 0), 127);
    const int cx1 = min(max(x1, 0), 127), cy1 = min(max(y1, 0), 127);
    const int o00 = ((cy0 << 7) | cx0) << 5;
    const int o10 = ((cy0 << 7) | cx1) << 5;
    const int o01 = ((cy1 << 7) | cx0) << 5;
    const int o11 = ((cy1 << 7) | cx1) << 5;
    const uint4 d00 = *(const uint4*)(xg + o00);
    const uint4 d10 = *(const uint4*)(xg + o10);
    const uint4 d01 = *(const uint4*)(xg + o01);
    const uint4 d11 = *(const uint4*)(xg + o11);
    a0 = fmaf(w00, bflo(d00.x), fmaf(w10, bflo(d10.x),
         fmaf(w01, bflo(d01.x), fmaf(w11, bflo(d11.x), a0))));
    a1 = fmaf(w00, bfhi(d00.x), fmaf(w10, bfhi(d10.x),
         fmaf(w01, bfhi(d01.x), fmaf(w11, bfhi(d11.x), a1))));
    a2 = fmaf(w00, bflo(d00.y), fmaf(w10, bflo(d10.y),
         fmaf(w01, bflo(d01.y), fmaf(w11, bflo(d11.y), a2))));
    a3 = fmaf(w00, bfhi(d00.y), fmaf(w10, bfhi(d10.y),
         fmaf(w01, bfhi(d01.y), fmaf(w11, bfhi(d11.y), a3))));
    a4 = fmaf(w00, bflo(d00.z), fmaf(w10, bflo(d10.z),
         fmaf(w01, bflo(d01.z), fmaf(w11, bflo(d11.z), a4))));
    a5 = fmaf(w00, bfhi(d00.z), fmaf(w10, bfhi(d10.z),
         fmaf(w01, bfhi(d01.z), fmaf(w11, bfhi(d11.z), a5))));
    a6 = fmaf(w00, bflo(d00.w), fmaf(w10, bflo(d10.w),
         fmaf(w01, bflo(d01.w), fmaf(w11, bflo(d11.w), a6))));
    a7 = fmaf(w00, bfhi(d00.w), fmaf(w10, bfhi(d10.w),
         fmaf(w01, bfhi(d01.w), fmaf(w11, bfhi(d11.w), a7))));
  }

  float* op = out + (size_t)q * 128 + (g << 5) + (sub << 3);
  float4 oa, ob;
  oa.x = a0; oa.y = a1; oa.z = a2; oa.w = a3;
  ob.x = a4; ob.y = a5; ob.z = a6; ob.w = a7;
  *(float4*)op = oa;
  *(float4*)(op + 4) = ob;
}

// ---------------- Tier-2 fallback: fp32 gather (R2-proven) ----------------
__global__ __launch_bounds__(256) void dcn_samp_f32(
    const float* __restrict__ x, const float* __restrict__ ws,
    float* __restrict__ out) {
  const int q = (blockIdx.x << 4) | (threadIdx.x >> 4);
  const int sub = threadIdx.x & 15;
  const int c = sub << 3;
  const int g = sub >> 2;
  const int b = q >> 14;
  const int h = (q >> 7) & 127;
  const int w = q & 127;
  const float* xb = x + ((size_t)b << 21) + c;
  const float* wsq = ws + q;
  float a0 = 0.f, a1 = 0.f, a2 = 0.f, a3 = 0.f;
  float a4 = 0.f, a5 = 0.f, a6 = 0.f, a7 = 0.f;
#pragma unroll
  for (int p = 0; p < 9; ++p) {
    const float offx = wsq[(size_t)(g * 18 + p * 2) * NPIX];
    const float offy = wsq[(size_t)(g * 18 + p * 2 + 1) * NPIX];
    const float mk = wsq[(size_t)(72 + g * 9 + p) * NPIX];
    const float px = (float)(w + p / 3) + offx;
    const float py = (float)(h + p % 3) + offy;
    const float fx = floorf(px), fy = floorf(py);
    const float tx = px - fx, ty = py - fy;
    const int x0 = (int)fx - 1, y0 = (int)fy - 1;
    const int x1 = x0 + 1, y1 = y0 + 1;
    const float ax0 = ((unsigned)x0 < 128u) ? (1.f - tx) : 0.f;
    const float ax1 = ((unsigned)x1 < 128u) ? tx : 0.f;
    const float ay0 = ((unsigned)y0 < 128u) ? (mk * (1.f - ty)) : 0.f;
    const float ay1 = ((unsigned)y1 < 128u) ? (mk * ty) : 0.f;
    const float w00 = ax0 * ay0, w10 = ax1 * ay0;
    const float w01 = ax0 * ay1, w11 = ax1 * ay1;
    const int cx0 = min(max(x0, 0), 127), cy0 = min(max(y0, 0), 127);
    const int cx1 = min(max(x1, 0), 127), cy1 = min(max(y1, 0), 127);
    const int o00 = (cy0 << 14) | (cx0 << 7), o10 = (cy0 << 14) | (cx1 << 7);
    const int o01 = (cy1 << 14) | (cx0 << 7), o11 = (cy1 << 14) | (cx1 << 7);
    const float4 v00a = *(const float4*)(xb + o00);
    const float4 v00b = *(const float4*)(xb + o00 + 4);
    const float4 v10a = *(const float4*)(xb + o10);
    const float4 v10b = *(const float4*)(xb + o10 + 4);
    const float4 v01a = *(const float4*)(xb + o01);
    const float4 v01b = *(const float4*)(xb + o01 + 4);
    const float4 v11a = *(const float4*)(xb + o11);
    const float4 v11b = *(const float4*)(xb + o11 + 4);
    a0 = fmaf(w00, v00a.x, fmaf(w10, v10a.x, fmaf(w01, v01a.x, fmaf(w11, v11a.x, a0))));
    a1 = fmaf(w00, v00a.y, fmaf(w10, v10a.y, fmaf(w01, v01a.y, fmaf(w11, v11a.y, a1))));
    a2 = fmaf(w00, v00a.z, fmaf(w10, v10a.z, fmaf(w01, v01a.z, fmaf(w11, v11a.z, a2))));
    a3 = fmaf(w00, v00a.w, fmaf(w10, v10a.w, fmaf(w01, v01a.w, fmaf(w11, v11a.w, a3))));
    a4 = fmaf(w00, v00b.x, fmaf(w10, v10b.x, fmaf(w01, v01b.x, fmaf(w11, v11b.x, a4))));
    a5 = fmaf(w00, v00b.y, fmaf(w10, v10b.y, fmaf(w01, v01b.y, fmaf(w11, v11b.y, a5))));
    a6 = fmaf(w00, v00b.z, fmaf(w10, v10b.z, fmaf(w01, v01b.z, fmaf(w11, v11b.z, a6))));
    a7 = fmaf(w00, v00b.w, fmaf(w10, v10b.w, fmaf(w01, v01b.w, fmaf(w11, v11b.w, a7))));
  }
  float4 oa, ob;
  oa.x = a0; oa.y = a1; oa.z = a2; oa.w = a3;
  ob.x = a4; ob.y = a5; ob.z = a6; ob.w = a7;
  float* op = out + (size_t)q * 128 + c;
  *(float4*)op = oa;
  *(float4*)(op + 4) = ob;
}

// ---------------- Tier-3 fallback: fully fused ----------------
__global__ __launch_bounds__(128) void dcn_fused(
    const float* __restrict__ x, const float* __restrict__ Woff,
    const float* __restrict__ boff, const float* __restrict__ Wmask,
    const float* __restrict__ bmask, float* __restrict__ out) {
  __shared__ float xs[128];
  __shared__ float res[108];
  __shared__ float msk[36];
  const int q = blockIdx.x;
  const int t = threadIdx.x;
  const int b = q >> 14, h = (q >> 7) & 127, w = q & 127;
  xs[t] = x[(size_t)q * 128 + t];
  __syncthreads();
  if (t < 108) {
    float a;
    const float* W;
    int ld;
    if (t < 72) {
      a = boff[t]; W = Woff + t; ld = 72;
    } else {
      a = bmask[t - 72]; W = Wmask + (t - 72); ld = 36;
    }
    for (int cc = 0; cc < 128; ++cc) a = fmaf(xs[cc], W[(size_t)cc * ld], a);
    res[t] = a;
  }
  __syncthreads();
  if (t < 4) {
    float mx = -1e30f;
    for (int p = 0; p < 9; ++p) mx = fmaxf(mx, res[72 + t * 9 + p]);
    float s = 0.f;
    float e[9];
    for (int p = 0; p < 9; ++p) {
      e[p] = __expf(res[72 + t * 9 + p] - mx);
      s += e[p];
    }
    for (int p = 0; p < 9; ++p) msk[t * 9 + p] = e[p] / s;
  }
  __syncthreads();
  const int g = t >> 5;
  const float* xb = x + ((size_t)b << 21) + t;
  float acc = 0.f;
#pragma unroll
  for (int p = 0; p < 9; ++p) {
    const float offx = res[g * 18 + p * 2];
    const float offy = res[g * 18 + p * 2 + 1];
    const float px = (float)(w + p / 3) + offx;
    const float py = (float)(h + p % 3) + offy;
    const float fx = floorf(px), fy = floorf(py);
    const float tx = px - fx, ty = py - fy;
    const int x0 = (int)fx - 1, y0 = (int)fy - 1;
    float sv = 0.f;
#define CORNER1(XI, YI, WT)                                       \
  if ((unsigned)(XI) < 128u && (unsigned)(YI) < 128u)             \
    sv = fmaf((WT), xb[((size_t)(YI) << 14) + ((size_t)(XI) << 7)], sv);
    CORNER1(x0, y0, (1.f - tx) * (1.f - ty))
    CORNER1(x0 + 1, y0, tx * (1.f - ty))
    CORNER1(x0, y0 + 1, (1.f - tx) * ty)
    CORNER1(x0 + 1, y0 + 1, tx * ty)
#undef CORNER1
    acc = fmaf(msk[g * 9 + p], sv, acc);
  }
  out[(size_t)q * 128 + t] = acc;
}

extern "C" void kernel_launch(void* const* d_in, const int* in_sizes, int n_in,
                              void* d_out, int out_size, void* d_ws,
                              size_t ws_size, hipStream_t stream) {
  const float* x = (const float*)d_in[0];
  const float* Woff = (const float*)d_in[1];
  const float* boff = (const float*)d_in[2];
  const float* Wmask = (const float*)d_in[3];
  const float* bmask = (const float*)d_in[4];
  float* out = (float*)d_out;
  const size_t need_ws = (size_t)NPIX * 108 * sizeof(float);
  const size_t need_full = need_ws + (size_t)NPIX * 128 * sizeof(ushort);
  if (ws_size >= need_full) {
    float* ws = (float*)d_ws;
    ushort* x16 = (ushort*)((char*)d_ws + need_ws);
    dcn_lin<<<1792, 256, 0, stream>>>(x, Woff, boff, Wmask, bmask, ws, x16);
    dcn_samp<<<4096, 256, 0, stream>>>(x16, ws, out);
  } else if (ws_size >= need_ws) {
    float* ws = (float*)d_ws;
    dcn_lin<<<1792, 256, 0, stream>>>(x, Woff, boff, Wmask, bmask, ws,
                                      (ushort*)nullptr);
    dcn_samp_f32<<<4096, 256, 0, stream>>>(x, ws, out);
  } else {
    dcn_fused<<<NPIX, 128, 0, stream>>>(x, Woff, boff, Wmask, bmask, out);
  }
}

// Round 6
// 62.736 us; speedup vs baseline: 2.8078x; 1.4504x over previous
//
#include <hip/hip_runtime.h>

// DCNv3 forward, fp32. Layouts (from the reference's view-reshapes):
//   x   : (B=4, H=128, W=128, C=128) flat — idx = ((b*128+h)*128+w)*128+c
//   out : same
//   W_off (128,72), b_off(72), W_mask(128,36), b_mask(36)
// ws: [0, 108*NPIX) floats : SoA ws[j*NPIX + pix]; j<72 = offsets (g,p,2),
//     j in [72,108) = mask LOGITS (softmax done in samp).
//     [108*NPIX floats ...) : x16 — bf16 copy of x, GROUP-PLANAR:
//     x16[((g*4+b)*16384 + y*128 + x)*32 + ch]  (ch in [0,32) within group)

#define NPIX 65536  // B*H*W

typedef unsigned int uint;
typedef unsigned short ushort;
typedef __attribute__((ext_vector_type(8))) short short8v;   // 8 bf16
typedef __attribute__((ext_vector_type(4))) float f32x4;

__device__ __forceinline__ ushort f2bf(float f) {
  uint u = __float_as_uint(f);
  u += 0x7FFFu + ((u >> 16) & 1u);  // RNE
  return (ushort)(u >> 16);
}
__device__ __forceinline__ uint pkbf(float lo, float hi) {
  return (uint)f2bf(lo) | ((uint)f2bf(hi) << 16);
}
__device__ __forceinline__ float bflo(uint d) { return __uint_as_float(d << 16); }
__device__ __forceinline__ float bfhi(uint d) { return __uint_as_float(d & 0xFFFF0000u); }

union U8 { uint u[4]; short8v v; };

// ---------------- Kernel A: MFMA linear layers + fused bf16 pack -----------
// grid 1024, block 256 (4 waves). Wave = 16 pixels x 112 cols (7 N-tiles),
// K=128 (4 k-tiles of 32). W^T staged in LDS as bf16 pairs, stride 68 u32
// (68%32=4 -> 2-way conflicts only, free). Bias folded into acc init.
// C/D layout (m89-verified): col=lane&15 (output col), row=(lane>>4)*4+reg
// (pixel) -> acc[nt] is 4 consecutive pixels of one ws plane = float4 store.
__global__ __launch_bounds__(256) void dcn_lin_mfma(
    const float* __restrict__ x, const float* __restrict__ Woff,
    const float* __restrict__ boff, const float* __restrict__ Wmask,
    const float* __restrict__ bmask, float* __restrict__ ws,
    ushort* __restrict__ x16) {
  __shared__ uint wt[112 * 68];
  __shared__ float bias_lds[112];
  const int pbase = blockIdx.x << 6;  // 64 pixels per block
  const int t = threadIdx.x;

  // ---- stage W^T (bf16 k-pairs) into LDS: wt[n*68 + k/2] ----
  {
    int n = t, row = 0;
    bool act = true;
    if (t >= 224) act = false;
    else if (t >= 112) { n = t - 112; row = 1; }
    if (act) {
      for (int kp = row; kp < 64; kp += 2) {
        const int k = kp << 1;
        float w0, w1;
        if (n < 72) {
          w0 = Woff[k * 72 + n];        w1 = Woff[k * 72 + 72 + n];
        } else if (n < 108) {
          w0 = Wmask[k * 36 + n - 72];  w1 = Wmask[k * 36 + 36 + n - 72];
        } else {
          w0 = 0.f; w1 = 0.f;
        }
        wt[n * 68 + kp] = pkbf(w0, w1);
      }
    }
    if (t < 112)
      bias_lds[t] = (t < 72) ? boff[t] : (t < 108 ? bmask[t - 72] : 0.f);
  }

  // ---- fused bf16 group-planar pack (no LDS dependency) ----
  if (x16) {
    const int pix2 = pbase + (t >> 2);
    const int quad = t & 3;  // = group
    const float* xp = x + (size_t)pix2 * 128 + (quad << 5);
    const int bb = pix2 >> 14, yx = pix2 & 16383;
    ushort* dst = x16 + ((((size_t)((quad << 2) | bb) << 14) | yx) << 5);
#pragma unroll
    for (int ck = 0; ck < 2; ++ck) {
      const float4 a = *(const float4*)(xp + ck * 16);
      const float4 b4 = *(const float4*)(xp + ck * 16 + 4);
      const float4 c4 = *(const float4*)(xp + ck * 16 + 8);
      const float4 d4 = *(const float4*)(xp + ck * 16 + 12);
      uint4 s0, s1;
      s0.x = pkbf(a.x, a.y);   s0.y = pkbf(a.z, a.w);
      s0.z = pkbf(b4.x, b4.y); s0.w = pkbf(b4.z, b4.w);
      s1.x = pkbf(c4.x, c4.y); s1.y = pkbf(c4.z, c4.w);
      s1.z = pkbf(d4.x, d4.y); s1.w = pkbf(d4.z, d4.w);
      *(uint4*)(dst + ck * 16) = s0;
      *(uint4*)(dst + ck * 16 + 8) = s1;
    }
  }
  __syncthreads();

  // ---- MFMA ----
  const int wv = t >> 6;
  const int lane = t & 63;
  const int lrow = lane & 15;  // A-row (pixel) / B-col (n)
  const int lhi = lane >> 4;   // k sub-block
  const int pixrow = pbase + (wv << 4) + lrow;

  U8 afr[4];
#pragma unroll
  for (int kt = 0; kt < 4; ++kt) {
    const float* ax = x + (size_t)pixrow * 128 + (kt << 5) + (lhi << 3);
    const float4 xa = *(const float4*)ax;
    const float4 xb4 = *(const float4*)(ax + 4);
    afr[kt].u[0] = pkbf(xa.x, xa.y);   afr[kt].u[1] = pkbf(xa.z, xa.w);
    afr[kt].u[2] = pkbf(xb4.x, xb4.y); afr[kt].u[3] = pkbf(xb4.z, xb4.w);
  }

  f32x4 acc[7];
#pragma unroll
  for (int nt = 0; nt < 7; ++nt) {
    const float bv = bias_lds[(nt << 4) + lrow];
    f32x4 a4 = {bv, bv, bv, bv};
#pragma unroll
    for (int kt = 0; kt < 4; ++kt) {
      U8 bfr;
      const uint4 bw =
          *(const uint4*)(wt + ((nt << 4) + lrow) * 68 + (kt << 4) + (lhi << 2));
      bfr.u[0] = bw.x; bfr.u[1] = bw.y; bfr.u[2] = bw.z; bfr.u[3] = bw.w;
      a4 = __builtin_amdgcn_mfma_f32_16x16x32_bf16(afr[kt].v, bfr.v, a4, 0, 0, 0);
    }
    acc[nt] = a4;
  }

  // ---- epilogue: dense float4 stores into SoA ws ----
  const int rowb = pbase + (wv << 4) + (lhi << 2);
#pragma unroll
  for (int nt = 0; nt < 7; ++nt) {
    const int n = (nt << 4) + lrow;
    if (n < 108) *(f32x4*)(ws + (size_t)n * NPIX + rowb) = acc[nt];
  }
}

// ---------------- Kernel B: bilinear gather from bf16 planar ---------------
// block 256 = 64 (pixel,group) pairs x 4 chunk-lanes; g = blockIdx&3.
// Mask softmax computed here from logits (9 loads + exp, redundant x4 lanes).
__global__ __launch_bounds__(256) void dcn_samp(
    const ushort* __restrict__ x16, const float* __restrict__ ws,
    float* __restrict__ out) {
  const int g = blockIdx.x & 3;
  const int pg = threadIdx.x >> 2;   // 0..63: pixel within block
  const int sub = threadIdx.x & 3;   // 16B chunk within the group slice
  const int q = ((blockIdx.x >> 2) << 6) | pg;
  const int b = q >> 14;
  const int h = (q >> 7) & 127;
  const int w = q & 127;
  const float* wsq = ws + q;
  const ushort* xg = x16 + (((size_t)((g << 2) | b) << 14) << 5) + (sub << 3);

  // softmax over the group's 9 logits
  float mk9[9];
  {
    float mx = -1e30f;
#pragma unroll
    for (int p = 0; p < 9; ++p) {
      mk9[p] = wsq[(size_t)(72 + g * 9 + p) * NPIX];
      mx = fmaxf(mx, mk9[p]);
    }
    float s = 0.f;
#pragma unroll
    for (int p = 0; p < 9; ++p) {
      mk9[p] = __expf(mk9[p] - mx);
      s += mk9[p];
    }
    const float sinv = 1.0f / s;
#pragma unroll
    for (int p = 0; p < 9; ++p) mk9[p] *= sinv;
  }

  float a0 = 0.f, a1 = 0.f, a2 = 0.f, a3 = 0.f;
  float a4 = 0.f, a5 = 0.f, a6 = 0.f, a7 = 0.f;

#pragma unroll
  for (int p = 0; p < 9; ++p) {
    const float offx = wsq[(size_t)(g * 18 + 2 * p) * NPIX];
    const float offy = wsq[(size_t)(g * 18 + 2 * p + 1) * NPIX];
    const float mk = mk9[p];
    const float px = (float)(w + p / 3) + offx;
    const float py = (float)(h + p % 3) + offy;
    const float fx = floorf(px), fy = floorf(py);
    const float tx = px - fx, ty = py - fy;
    const int x0 = (int)fx - 1, y0 = (int)fy - 1;
    const int x1 = x0 + 1, y1 = y0 + 1;
    const float ax0 = ((unsigned)x0 < 128u) ? (1.f - tx) : 0.f;
    const float ax1 = ((unsigned)x1 < 128u) ? tx : 0.f;
    const float ay0 = ((unsigned)y0 < 128u) ? (mk * (1.f - ty)) : 0.f;
    const float ay1 = ((unsigned)y1 < 128u) ? (mk * ty) : 0.f;
    const float w00 = ax0 * ay0, w10 = ax1 * ay0;
    const float w01 = ax0 * ay1, w11 = ax1 * ay1;
    const int cx0 = min(max(x0, 0), 127), cy0 = min(max(y0, 0), 127);
    const int cx1 = min(max(x1, 0), 127), cy1 = min(max(y1, 0), 127);
    const int o00 = ((cy0 << 7) | cx0) << 5;
    const int o10 = ((cy0 << 7) | cx1) << 5;
    const int o01 = ((cy1 << 7) | cx0) << 5;
    const int o11 = ((cy1 << 7) | cx1) << 5;
    const uint4 d00 = *(const uint4*)(xg + o00);
    const uint4 d10 = *(const uint4*)(xg + o10);
    const uint4 d01 = *(const uint4*)(xg + o01);
    const uint4 d11 = *(const uint4*)(xg + o11);
    a0 = fmaf(w00, bflo(d00.x), fmaf(w10, bflo(d10.x),
         fmaf(w01, bflo(d01.x), fmaf(w11, bflo(d11.x), a0))));
    a1 = fmaf(w00, bfhi(d00.x), fmaf(w10, bfhi(d10.x),
         fmaf(w01, bfhi(d01.x), fmaf(w11, bfhi(d11.x), a1))));
    a2 = fmaf(w00, bflo(d00.y), fmaf(w10, bflo(d10.y),
         fmaf(w01, bflo(d01.y), fmaf(w11, bflo(d11.y), a2))));
    a3 = fmaf(w00, bfhi(d00.y), fmaf(w10, bfhi(d10.y),
         fmaf(w01, bfhi(d01.y), fmaf(w11, bfhi(d11.y), a3))));
    a4 = fmaf(w00, bflo(d00.z), fmaf(w10, bflo(d10.z),
         fmaf(w01, bflo(d01.z), fmaf(w11, bflo(d11.z), a4))));
    a5 = fmaf(w00, bfhi(d00.z), fmaf(w10, bfhi(d10.z),
         fmaf(w01, bfhi(d01.z), fmaf(w11, bfhi(d11.z), a5))));
    a6 = fmaf(w00, bflo(d00.w), fmaf(w10, bflo(d10.w),
         fmaf(w01, bflo(d01.w), fmaf(w11, bflo(d11.w), a6))));
    a7 = fmaf(w00, bfhi(d00.w), fmaf(w10, bfhi(d10.w),
         fmaf(w01, bfhi(d01.w), fmaf(w11, bfhi(d11.w), a7))));
  }

  float* op = out + (size_t)q * 128 + (g << 5) + (sub << 3);
  float4 oa, ob;
  oa.x = a0; oa.y = a1; oa.z = a2; oa.w = a3;
  ob.x = a4; ob.y = a5; ob.z = a6; ob.w = a7;
  *(float4*)op = oa;
  *(float4*)(op + 4) = ob;
}

// ---------------- Tier-2 fallback: legacy VALU lin (with softmax) ----------
__global__ __launch_bounds__(256) void dcn_lin(
    const float* __restrict__ x, const float* __restrict__ Woff,
    const float* __restrict__ boff, const float* __restrict__ Wmask,
    const float* __restrict__ bmask, float* __restrict__ ws) {
  const int jg = blockIdx.x >> 8;
  const int pix = ((blockIdx.x & 255) << 8) | threadIdx.x;
  const float* W;
  const float* bias;
  int ldw, obase;
  if (jg == 0) {
    W = Woff; bias = boff; ldw = 72; obase = 0;
  } else if (jg == 1) {
    W = Woff + 36; bias = boff + 36; ldw = 72; obase = 36;
  } else {
    W = Wmask; bias = bmask; ldw = 36; obase = 72;
  }
  float acc[36];
#pragma unroll
  for (int j = 0; j < 36; ++j) acc[j] = bias[j];
  const float* xp = x + (size_t)pix * 128;
  for (int c0 = 0; c0 < 128; c0 += 8) {
    float xr[8];
    *(float4*)(xr) = *(const float4*)(xp + c0);
    *(float4*)(xr + 4) = *(const float4*)(xp + c0 + 4);
#pragma unroll
    for (int cc = 0; cc < 8; ++cc) {
      const float xc = xr[cc];
      const float* wr = W + (size_t)(c0 + cc) * ldw;
#pragma unroll
      for (int j = 0; j < 36; ++j) acc[j] = fmaf(xc, wr[j], acc[j]);
    }
  }
  if (jg == 2) {
#pragma unroll
    for (int g = 0; g < 4; ++g) {
      float mx = acc[g * 9];
#pragma unroll
      for (int p = 1; p < 9; ++p) mx = fmaxf(mx, acc[g * 9 + p]);
      float s = 0.f;
#pragma unroll
      for (int p = 0; p < 9; ++p) {
        acc[g * 9 + p] = __expf(acc[g * 9 + p] - mx);
        s += acc[g * 9 + p];
      }
      const float sinv = 1.0f / s;
#pragma unroll
      for (int p = 0; p < 9; ++p) acc[g * 9 + p] *= sinv;
    }
  }
#pragma unroll
  for (int j = 0; j < 36; ++j) ws[(size_t)(obase + j) * NPIX + pix] = acc[j];
}

// ---------------- Tier-2 fallback: fp32 gather (R2-proven) ----------------
__global__ __launch_bounds__(256) void dcn_samp_f32(
    const float* __restrict__ x, const float* __restrict__ ws,
    float* __restrict__ out) {
  const int q = (blockIdx.x << 4) | (threadIdx.x >> 4);
  const int sub = threadIdx.x & 15;
  const int c = sub << 3;
  const int g = sub >> 2;
  const int b = q >> 14;
  const int h = (q >> 7) & 127;
  const int w = q & 127;
  const float* xb = x + ((size_t)b << 21) + c;
  const float* wsq = ws + q;
  float a0 = 0.f, a1 = 0.f, a2 = 0.f, a3 = 0.f;
  float a4 = 0.f, a5 = 0.f, a6 = 0.f, a7 = 0.f;
#pragma unroll
  for (int p = 0; p < 9; ++p) {
    const float offx = wsq[(size_t)(g * 18 + p * 2) * NPIX];
    const float offy = wsq[(size_t)(g * 18 + p * 2 + 1) * NPIX];
    const float mk = wsq[(size_t)(72 + g * 9 + p) * NPIX];
    const float px = (float)(w + p / 3) + offx;
    const float py = (float)(h + p % 3) + offy;
    const float fx = floorf(px), fy = floorf(py);
    const float tx = px - fx, ty = py - fy;
    const int x0 = (int)fx - 1, y0 = (int)fy - 1;
    const int x1 = x0 + 1, y1 = y0 + 1;
    const float ax0 = ((unsigned)x0 < 128u) ? (1.f - tx) : 0.f;
    const float ax1 = ((unsigned)x1 < 128u) ? tx : 0.f;
    const float ay0 = ((unsigned)y0 < 128u) ? (mk * (1.f - ty)) : 0.f;
    const float ay1 = ((unsigned)y1 < 128u) ? (mk * ty) : 0.f;
    const float w00 = ax0 * ay0, w10 = ax1 * ay0;
    const float w01 = ax0 * ay1, w11 = ax1 * ay1;
    const int cx0 = min(max(x0, 0), 127), cy0 = min(max(y0, 0), 127);
    const int cx1 = min(max(x1, 0), 127), cy1 = min(max(y1, 0), 127);
    const int o00 = (cy0 << 14) | (cx0 << 7), o10 = (cy0 << 14) | (cx1 << 7);
    const int o01 = (cy1 << 14) | (cx0 << 7), o11 = (cy1 << 14) | (cx1 << 7);
    const float4 v00a = *(const float4*)(xb + o00);
    const float4 v00b = *(const float4*)(xb + o00 + 4);
    const float4 v10a = *(const float4*)(xb + o10);
    const float4 v10b = *(const float4*)(xb + o10 + 4);
    const float4 v01a = *(const float4*)(xb + o01);
    const float4 v01b = *(const float4*)(xb + o01 + 4);
    const float4 v11a = *(const float4*)(xb + o11);
    const float4 v11b = *(const float4*)(xb + o11 + 4);
    a0 = fmaf(w00, v00a.x, fmaf(w10, v10a.x, fmaf(w01, v01a.x, fmaf(w11, v11a.x, a0))));
    a1 = fmaf(w00, v00a.y, fmaf(w10, v10a.y, fmaf(w01, v01a.y, fmaf(w11, v11a.y, a1))));
    a2 = fmaf(w00, v00a.z, fmaf(w10, v10a.z, fmaf(w01, v01a.z, fmaf(w11, v11a.z, a2))));
    a3 = fmaf(w00, v00a.w, fmaf(w10, v10a.w, fmaf(w01, v01a.w, fmaf(w11, v11a.w, a3))));
    a4 = fmaf(w00, v00b.x, fmaf(w10, v10b.x, fmaf(w01, v01b.x, fmaf(w11, v11b.x, a4))));
    a5 = fmaf(w00, v00b.y, fmaf(w10, v10b.y, fmaf(w01, v01b.y, fmaf(w11, v11b.y, a5))));
    a6 = fmaf(w00, v00b.z, fmaf(w10, v10b.z, fmaf(w01, v01b.z, fmaf(w11, v11b.z, a6))));
    a7 = fmaf(w00, v00b.w, fmaf(w10, v10b.w, fmaf(w01, v01b.w, fmaf(w11, v11b.w, a7))));
  }
  float4 oa, ob;
  oa.x = a0; oa.y = a1; oa.z = a2; oa.w = a3;
  ob.x = a4; ob.y = a5; ob.z = a6; ob.w = a7;
  float* op = out + (size_t)q * 128 + c;
  *(float4*)op = oa;
  *(float4*)(op + 4) = ob;
}

// ---------------- Tier-3 fallback: fully fused ----------------
__global__ __launch_bounds__(128) void dcn_fused(
    const float* __restrict__ x, const float* __restrict__ Woff,
    const float* __restrict__ boff, const float* __restrict__ Wmask,
    const float* __restrict__ bmask, float* __restrict__ out) {
  __shared__ float xs[128];
  __shared__ float res[108];
  __shared__ float msk[36];
  const int q = blockIdx.x;
  const int t = threadIdx.x;
  const int b = q >> 14, h = (q >> 7) & 127, w = q & 127;
  xs[t] = x[(size_t)q * 128 + t];
  __syncthreads();
  if (t < 108) {
    float a;
    const float* W;
    int ld;
    if (t < 72) {
      a = boff[t]; W = Woff + t; ld = 72;
    } else {
      a = bmask[t - 72]; W = Wmask + (t - 72); ld = 36;
    }
    for (int cc = 0; cc < 128; ++cc) a = fmaf(xs[cc], W[(size_t)cc * ld], a);
    res[t] = a;
  }
  __syncthreads();
  if (t < 4) {
    float mx = -1e30f;
    for (int p = 0; p < 9; ++p) mx = fmaxf(mx, res[72 + t * 9 + p]);
    float s = 0.f;
    float e[9];
    for (int p = 0; p < 9; ++p) {
      e[p] = __expf(res[72 + t * 9 + p] - mx);
      s += e[p];
    }
    for (int p = 0; p < 9; ++p) msk[t * 9 + p] = e[p] / s;
  }
  __syncthreads();
  const int g = t >> 5;
  const float* xb = x + ((size_t)b << 21) + t;
  float acc = 0.f;
#pragma unroll
  for (int p = 0; p < 9; ++p) {
    const float offx = res[g * 18 + p * 2];
    const float offy = res[g * 18 + p * 2 + 1];
    const float px = (float)(w + p / 3) + offx;
    const float py = (float)(h + p % 3) + offy;
    const float fx = floorf(px), fy = floorf(py);
    const float tx = px - fx, ty = py - fy;
    const int x0 = (int)fx - 1, y0 = (int)fy - 1;
    float sv = 0.f;
#define CORNER1(XI, YI, WT)                                       \
  if ((unsigned)(XI) < 128u && (unsigned)(YI) < 128u)             \
    sv = fmaf((WT), xb[((size_t)(YI) << 14) + ((size_t)(XI) << 7)], sv);
    CORNER1(x0, y0, (1.f - tx) * (1.f - ty))
    CORNER1(x0 + 1, y0, tx * (1.f - ty))
    CORNER1(x0, y0 + 1, (1.f - tx) * ty)
    CORNER1(x0 + 1, y0 + 1, tx * ty)
#undef CORNER1
    acc = fmaf(msk[g * 9 + p], sv, acc);
  }
  out[(size_t)q * 128 + t] = acc;
}

extern "C" void kernel_launch(void* const* d_in, const int* in_sizes, int n_in,
                              void* d_out, int out_size, void* d_ws,
                              size_t ws_size, hipStream_t stream) {
  const float* x = (const float*)d_in[0];
  const float* Woff = (const float*)d_in[1];
  const float* boff = (const float*)d_in[2];
  const float* Wmask = (const float*)d_in[3];
  const float* bmask = (const float*)d_in[4];
  float* out = (float*)d_out;
  const size_t need_ws = (size_t)NPIX * 108 * sizeof(float);
  const size_t need_full = need_ws + (size_t)NPIX * 128 * sizeof(ushort);
  if (ws_size >= need_full) {
    float* ws = (float*)d_ws;
    ushort* x16 = (ushort*)((char*)d_ws + need_ws);
    dcn_lin_mfma<<<1024, 256, 0, stream>>>(x, Woff, boff, Wmask, bmask, ws, x16);
    dcn_samp<<<4096, 256, 0, stream>>>(x16, ws, out);
  } else if (ws_size >= need_ws) {
    float* ws = (float*)d_ws;
    dcn_lin<<<768, 256, 0, stream>>>(x, Woff, boff, Wmask, bmask, ws);
    dcn_samp_f32<<<4096, 256, 0, stream>>>(x, ws, out);
  } else {
    dcn_fused<<<NPIX, 128, 0, stream>>>(x, Woff, boff, Wmask, bmask, out);
  }
}